// Round 1
// baseline (1526.959 us; speedup 1.0000x reference)
//
#include <hip/hip_runtime.h>

#define N_NODES 100000
#define N_EDGES 1600000
#define N_GRAPHS 2048
#define HID 64
#define IN_F 14
#define N_CLS 2
#define EPS 1e-5f

// ---------------- kernels ----------------

__global__ __launch_bounds__(256) void fill_f32(float* p, float v, int n) {
    int i = blockIdx.x * blockDim.x + threadIdx.x;
    if (i < n) p[i] = v;
}

// deg[col[e]] += w[e]  (self-loop "+1" pre-filled by fill_f32)
__global__ __launch_bounds__(256) void deg_kernel(const int* __restrict__ col,
                                                  const float* __restrict__ w,
                                                  float* __restrict__ deg, int E) {
    int stride = gridDim.x * blockDim.x;
    for (int e = blockIdx.x * blockDim.x + threadIdx.x; e < E; e += stride)
        atomicAdd(&deg[col[e]], w[e]);
}

__global__ __launch_bounds__(256) void dinv_kernel(float* __restrict__ deg, int n) {
    int i = blockIdx.x * blockDim.x + threadIdx.x;
    if (i < n) deg[i] = rsqrtf(deg[i]);
}

// xw[n, f] = sum_k h[n,k] * W[k,f].  Thread = (wave node-stride, lane = f).
// W column kept in registers; h[n,k] is a wave-uniform broadcast load.
template <int K>
__global__ __launch_bounds__(256) void gemm_kernel(const float* __restrict__ h,
                                                   const float* __restrict__ W,
                                                   float* __restrict__ xw, int n_nodes) {
    int f = threadIdx.x & 63;
    float wcol[K];
#pragma unroll
    for (int k = 0; k < K; k++) wcol[k] = W[k * HID + f];
    int wave = (blockIdx.x * blockDim.x + threadIdx.x) >> 6;
    int nwaves = (gridDim.x * blockDim.x) >> 6;
    for (int n = wave; n < n_nodes; n += nwaves) {
        const float* hr = h + (size_t)n * K;
        float acc = 0.f;
#pragma unroll
        for (int k = 0; k < K; k++) acc += hr[k] * wcol[k];
        xw[(size_t)n * HID + f] = acc;
    }
}

// acc[col, f] += dinv[row]*w*dinv[col] * xw[row, f]   (wave per edge, lane = f)
__global__ __launch_bounds__(256) void scatter_kernel(const int* __restrict__ row,
                                                      const int* __restrict__ col,
                                                      const float* __restrict__ w,
                                                      const float* __restrict__ dinv,
                                                      const float* __restrict__ xw,
                                                      float* __restrict__ acc, int E) {
    int g = blockIdx.x * blockDim.x + threadIdx.x;
    int f = g & 63;
    int stride = (gridDim.x * blockDim.x) >> 6;
    for (int e = g >> 6; e < E; e += stride) {
        int r = row[e], c = col[e];
        float nrm = dinv[r] * w[e] * dinv[c];
        atomicAdd(&acc[(size_t)c * HID + f], nrm * xw[(size_t)r * HID + f]);
    }
}

// v = acc + dinv^2 * xw + b;  acc = v;  stats[f] += sum v, stats[64+f] += sum v^2
__global__ __launch_bounds__(256) void self_stats_kernel(float* __restrict__ acc,
                                                         const float* __restrict__ xw,
                                                         const float* __restrict__ dinv,
                                                         const float* __restrict__ b,
                                                         float* __restrict__ stats,
                                                         int n_nodes) {
    int g = blockIdx.x * blockDim.x + threadIdx.x;
    int f = g & 63;
    int wave = g >> 6;
    int nwaves = (gridDim.x * blockDim.x) >> 6;
    float bf = b[f];
    float s = 0.f, s2 = 0.f;
    for (int n = wave; n < n_nodes; n += nwaves) {
        float di = dinv[n];
        size_t idx = (size_t)n * HID + f;
        float v = acc[idx] + di * di * xw[idx] + bf;
        acc[idx] = v;
        s += v;
        s2 += v * v;
    }
    __shared__ float ls[256], ls2[256];
    ls[threadIdx.x] = s;
    ls2[threadIdx.x] = s2;
    __syncthreads();
    if (threadIdx.x < 64) {
        float a = ls[threadIdx.x] + ls[threadIdx.x + 64] + ls[threadIdx.x + 128] + ls[threadIdx.x + 192];
        float a2 = ls2[threadIdx.x] + ls2[threadIdx.x + 64] + ls2[threadIdx.x + 128] + ls2[threadIdx.x + 192];
        atomicAdd(&stats[threadIdx.x], a);
        atomicAdd(&stats[64 + threadIdx.x], a2);
    }
}

__global__ __launch_bounds__(256) void bn_relu_kernel(float* __restrict__ acc,
                                                      const float* __restrict__ stats,
                                                      const float* __restrict__ gamma,
                                                      const float* __restrict__ beta,
                                                      int n_nodes) {
    int g = blockIdx.x * blockDim.x + threadIdx.x;
    int f = g & 63;
    float mean = stats[f] * (1.0f / N_NODES);
    float var = stats[64 + f] * (1.0f / N_NODES) - mean * mean;
    float sc = gamma[f] * rsqrtf(var + EPS);
    float sh = beta[f] - mean * sc;
    int wave = g >> 6;
    int nwaves = (gridDim.x * blockDim.x) >> 6;
    for (int n = wave; n < n_nodes; n += nwaves) {
        size_t idx = (size_t)n * HID + f;
        float v = acc[idx] * sc + sh;
        acc[idx] = v > 0.f ? v : 0.f;
    }
}

__global__ __launch_bounds__(256) void segment_kernel(const float* __restrict__ h,
                                                      const int* __restrict__ batch,
                                                      float* __restrict__ gemb, int n_nodes) {
    int g = blockIdx.x * blockDim.x + threadIdx.x;
    int f = g & 63;
    int wave = g >> 6;
    int nwaves = (gridDim.x * blockDim.x) >> 6;
    for (int n = wave; n < n_nodes; n += nwaves) {
        int b = batch[n];
        atomicAdd(&gemb[(size_t)b * HID + f], h[(size_t)n * HID + f]);
    }
}

__global__ __launch_bounds__(256) void final_kernel(const float* __restrict__ gemb,
                                                    const float* __restrict__ fcW,
                                                    const float* __restrict__ fcb,
                                                    float* __restrict__ out) {
    int g = blockIdx.x * blockDim.x + threadIdx.x;
    if (g >= N_GRAPHS * N_CLS) return;
    int gr = g >> 1, c = g & 1;
    float acc = fcb[c];
#pragma unroll
    for (int k = 0; k < HID; k++) acc += gemb[gr * HID + k] * fcW[k * N_CLS + c];
    out[g] = acc;
}

// ---------------- launch ----------------

extern "C" void kernel_launch(void* const* d_in, const int* in_sizes, int n_in,
                              void* d_out, int out_size, void* d_ws, size_t ws_size,
                              hipStream_t stream) {
    const float* x    = (const float*)d_in[0];
    const int*   ei   = (const int*)d_in[1];
    const int*   batch= (const int*)d_in[2];
    const float* ew   = (const float*)d_in[3];
    const float* W1   = (const float*)d_in[4];
    const float* b1   = (const float*)d_in[5];
    const float* W2   = (const float*)d_in[6];
    const float* b2   = (const float*)d_in[7];
    const float* W3   = (const float*)d_in[8];
    const float* b3   = (const float*)d_in[9];
    const float* g1   = (const float*)d_in[10];
    const float* bt1  = (const float*)d_in[11];
    const float* g2   = (const float*)d_in[12];
    const float* bt2  = (const float*)d_in[13];
    const float* g3   = (const float*)d_in[14];
    const float* bt3  = (const float*)d_in[15];
    const float* fcW  = (const float*)d_in[16];
    const float* fcb  = (const float*)d_in[17];

    const int* row = ei;
    const int* col = ei + N_EDGES;

    // d_out layout: out [2048*2] | node_embs [100000*64] | graph_emb [2048*64]
    float* out_head  = (float*)d_out;
    float* node_embs = out_head + N_GRAPHS * N_CLS;
    float* gemb      = node_embs + (size_t)N_NODES * HID;

    // ws layout: xw [100000*64] | dinv [100000] | stats [128]
    float* xw    = (float*)d_ws;
    float* dinv  = xw + (size_t)N_NODES * HID;
    float* stats = dinv + N_NODES;

    const int B = 256;
    const int gN  = (N_NODES + B - 1) / B;      // per-node 1D kernels
    const int gGS = 1024;                        // grid-stride kernels
    const int gSC = 2048;                        // scatter

    // degree -> dinv (shared by all 3 layers)
    fill_f32<<<gN, B, 0, stream>>>(dinv, 1.0f, N_NODES);
    deg_kernel<<<gGS, B, 0, stream>>>(col, ew, dinv, N_EDGES);
    dinv_kernel<<<gN, B, 0, stream>>>(dinv, N_NODES);

    float* acc = node_embs;  // accumulator reused each layer; ends as h3 = node_embs output

    // ---- layer 1 (K = IN_F) ----
    gemm_kernel<IN_F><<<gGS, B, 0, stream>>>(x, W1, xw, N_NODES);
    hipMemsetAsync(acc, 0, (size_t)N_NODES * HID * sizeof(float), stream);
    scatter_kernel<<<gSC, B, 0, stream>>>(row, col, ew, dinv, xw, acc, N_EDGES);
    hipMemsetAsync(stats, 0, 128 * sizeof(float), stream);
    self_stats_kernel<<<gGS, B, 0, stream>>>(acc, xw, dinv, b1, stats, N_NODES);
    bn_relu_kernel<<<gGS, B, 0, stream>>>(acc, stats, g1, bt1, N_NODES);

    // ---- layer 2 ----
    gemm_kernel<HID><<<gGS, B, 0, stream>>>(acc, W2, xw, N_NODES);
    hipMemsetAsync(acc, 0, (size_t)N_NODES * HID * sizeof(float), stream);
    scatter_kernel<<<gSC, B, 0, stream>>>(row, col, ew, dinv, xw, acc, N_EDGES);
    hipMemsetAsync(stats, 0, 128 * sizeof(float), stream);
    self_stats_kernel<<<gGS, B, 0, stream>>>(acc, xw, dinv, b2, stats, N_NODES);
    bn_relu_kernel<<<gGS, B, 0, stream>>>(acc, stats, g2, bt2, N_NODES);

    // ---- layer 3 ----
    gemm_kernel<HID><<<gGS, B, 0, stream>>>(acc, W3, xw, N_NODES);
    hipMemsetAsync(acc, 0, (size_t)N_NODES * HID * sizeof(float), stream);
    scatter_kernel<<<gSC, B, 0, stream>>>(row, col, ew, dinv, xw, acc, N_EDGES);
    hipMemsetAsync(stats, 0, 128 * sizeof(float), stream);
    self_stats_kernel<<<gGS, B, 0, stream>>>(acc, xw, dinv, b3, stats, N_NODES);
    bn_relu_kernel<<<gGS, B, 0, stream>>>(acc, stats, g3, bt3, N_NODES);

    // ---- readout ----
    hipMemsetAsync(gemb, 0, (size_t)N_GRAPHS * HID * sizeof(float), stream);
    segment_kernel<<<gGS, B, 0, stream>>>(node_embs, batch, gemb, N_NODES);
    final_kernel<<<(N_GRAPHS * N_CLS + B - 1) / B, B, 0, stream>>>(gemb, fcW, fcb, out_head);
}

// Round 2
// 1085.282 us; speedup vs baseline: 1.4070x; 1.4070x over previous
//
#include <hip/hip_runtime.h>

#define N_NODES 100000
#define N_EDGES 1600000
#define N_GRAPHS 2048
#define HID 64
#define IN_F 14
#define N_CLS 2
#define EPS 1e-5f

// ---------------- small utility kernels ----------------

__global__ __launch_bounds__(256) void fill_f32(float* p, float v, int n) {
    int i = blockIdx.x * blockDim.x + threadIdx.x;
    if (i < n) p[i] = v;
}

// deg[col[e]] += w[e]  (self-loop "+1" pre-filled by fill_f32)
__global__ __launch_bounds__(256) void deg_kernel(const int* __restrict__ col,
                                                  const float* __restrict__ w,
                                                  float* __restrict__ deg, int E) {
    int stride = gridDim.x * blockDim.x;
    for (int e = blockIdx.x * blockDim.x + threadIdx.x; e < E; e += stride)
        atomicAdd(&deg[col[e]], w[e]);
}

__global__ __launch_bounds__(256) void dinv_kernel(float* __restrict__ deg, int n) {
    int i = blockIdx.x * blockDim.x + threadIdx.x;
    if (i < n) deg[i] = rsqrtf(deg[i]);
}

// ---------------- CSR build (counting sort by dst) ----------------

__global__ __launch_bounds__(256) void hist_kernel(const int* __restrict__ col,
                                                   int* __restrict__ cnt, int E) {
    int stride = gridDim.x * blockDim.x;
    for (int e = blockIdx.x * blockDim.x + threadIdx.x; e < E; e += stride)
        atomicAdd(&cnt[col[e]], 1);
}

// per-block sums of cnt (256 elements per block)
__global__ __launch_bounds__(256) void blocksum_kernel(const int* __restrict__ cnt,
                                                       int* __restrict__ bsum, int n) {
    __shared__ int ls[256];
    int i = blockIdx.x * 256 + threadIdx.x;
    ls[threadIdx.x] = (i < n) ? cnt[i] : 0;
    __syncthreads();
    for (int off = 128; off > 0; off >>= 1) {
        if (threadIdx.x < off) ls[threadIdx.x] += ls[threadIdx.x + off];
        __syncthreads();
    }
    if (threadIdx.x == 0) bsum[blockIdx.x] = ls[0];
}

// single-block exclusive scan of bsum[nb] (nb <= 512)
__global__ __launch_bounds__(512) void topscan_kernel(int* __restrict__ bsum, int nb) {
    __shared__ int ls[512];
    int t = threadIdx.x;
    int v = (t < nb) ? bsum[t] : 0;
    ls[t] = v;
    __syncthreads();
    for (int off = 1; off < 512; off <<= 1) {
        int x = ls[t];
        if (t >= off) x += ls[t - off];
        __syncthreads();
        ls[t] = x;
        __syncthreads();
    }
    if (t < nb) bsum[t] = ls[t] - v;  // exclusive
}

// per-block exclusive scan of cnt + block offset -> ptr, cursor
__global__ __launch_bounds__(256) void blockscan_kernel(const int* __restrict__ cnt,
                                                        const int* __restrict__ bsum,
                                                        int* __restrict__ ptr,
                                                        int* __restrict__ cursor, int n) {
    __shared__ int ls[256];
    int i = blockIdx.x * 256 + threadIdx.x;
    int v = (i < n) ? cnt[i] : 0;
    ls[threadIdx.x] = v;
    __syncthreads();
    for (int off = 1; off < 256; off <<= 1) {
        int x = ls[threadIdx.x];
        if (threadIdx.x >= off) x += ls[threadIdx.x - off];
        __syncthreads();
        ls[threadIdx.x] = x;
        __syncthreads();
    }
    if (i < n) {
        int excl = ls[threadIdx.x] - v + bsum[blockIdx.x];
        ptr[i] = excl;
        cursor[i] = excl;
    }
}

// permute edges into dst-sorted order; precompute per-edge norm
__global__ __launch_bounds__(256) void scatter_edges_kernel(const int* __restrict__ row,
                                                            const int* __restrict__ col,
                                                            const float* __restrict__ w,
                                                            const float* __restrict__ dinv,
                                                            int* __restrict__ cursor,
                                                            int* __restrict__ srcs,
                                                            float* __restrict__ nrms, int E) {
    int stride = gridDim.x * blockDim.x;
    for (int e = blockIdx.x * blockDim.x + threadIdx.x; e < E; e += stride) {
        int r = row[e], c = col[e];
        int pos = atomicAdd(&cursor[c], 1);
        srcs[pos] = r;
        nrms[pos] = dinv[r] * w[e] * dinv[c];
    }
}

// ---------------- dense GEMM xw = h @ W ----------------

template <int K>
__global__ __launch_bounds__(256) void gemm_kernel(const float* __restrict__ h,
                                                   const float* __restrict__ W,
                                                   float* __restrict__ xw, int n_nodes) {
    int f = threadIdx.x & 63;
    float wcol[K];
#pragma unroll
    for (int k = 0; k < K; k++) wcol[k] = W[k * HID + f];
    int wave = (blockIdx.x * blockDim.x + threadIdx.x) >> 6;
    int nwaves = (gridDim.x * blockDim.x) >> 6;
    for (int n = wave; n < n_nodes; n += nwaves) {
        const float* hr = h + (size_t)n * K;
        float acc = 0.f;
#pragma unroll
        for (int k = 0; k < K; k++) acc += hr[k] * wcol[k];
        xw[(size_t)n * HID + f] = acc;
    }
}

// ---------------- fused CSR gather + self-loop + bias + BN stats ----------------
// wave per dst node (lane = feature); edge (src,nrm) loaded coalesced, shfl-broadcast
__global__ __launch_bounds__(256) void gather_stats_kernel(const int* __restrict__ ptr,
                                                           const int* __restrict__ cnt,
                                                           const int* __restrict__ srcs,
                                                           const float* __restrict__ nrms,
                                                           const float* __restrict__ xw,
                                                           const float* __restrict__ dinv,
                                                           const float* __restrict__ b,
                                                           float* __restrict__ h,
                                                           float* __restrict__ stats,
                                                           int n_nodes) {
    int g = blockIdx.x * blockDim.x + threadIdx.x;
    int f = g & 63;
    int lane = threadIdx.x & 63;
    int wave = g >> 6;
    int nwaves = (gridDim.x * blockDim.x) >> 6;
    float bf = b[f];
    float s = 0.f, s2 = 0.f;
    for (int n = wave; n < n_nodes; n += nwaves) {
        int beg = ptr[n];
        int c = cnt[n];
        float acc = 0.f;
        for (int j0 = 0; j0 < c; j0 += 64) {
            int m = c - j0;
            if (m > 64) m = 64;
            int sv = 0;
            float nv = 0.f;
            if (lane < m) {
                sv = srcs[beg + j0 + lane];
                nv = nrms[beg + j0 + lane];
            }
            for (int j = 0; j < m; j++) {
                int src = __shfl(sv, j);
                float nm = __shfl(nv, j);
                acc += nm * xw[(size_t)src * HID + f];
            }
        }
        float di = dinv[n];
        float v = acc + di * di * xw[(size_t)n * HID + f] + bf;
        h[(size_t)n * HID + f] = v;
        s += v;
        s2 += v * v;
    }
    __shared__ float ls[256], ls2[256];
    ls[threadIdx.x] = s;
    ls2[threadIdx.x] = s2;
    __syncthreads();
    if (threadIdx.x < 64) {
        float a = ls[threadIdx.x] + ls[threadIdx.x + 64] + ls[threadIdx.x + 128] + ls[threadIdx.x + 192];
        float a2 = ls2[threadIdx.x] + ls2[threadIdx.x + 64] + ls2[threadIdx.x + 128] + ls2[threadIdx.x + 192];
        atomicAdd(&stats[threadIdx.x], a);
        atomicAdd(&stats[64 + threadIdx.x], a2);
    }
}

// ---------------- BN apply + ReLU ----------------

__global__ __launch_bounds__(256) void bn_relu_kernel(float* __restrict__ h,
                                                      const float* __restrict__ stats,
                                                      const float* __restrict__ gamma,
                                                      const float* __restrict__ beta,
                                                      int n_nodes) {
    int g = blockIdx.x * blockDim.x + threadIdx.x;
    int f = g & 63;
    float mean = stats[f] * (1.0f / N_NODES);
    float var = stats[64 + f] * (1.0f / N_NODES) - mean * mean;
    float sc = gamma[f] * rsqrtf(var + EPS);
    float sh = beta[f] - mean * sc;
    int wave = g >> 6;
    int nwaves = (gridDim.x * blockDim.x) >> 6;
    for (int n = wave; n < n_nodes; n += nwaves) {
        size_t idx = (size_t)n * HID + f;
        float v = h[idx] * sc + sh;
        h[idx] = v > 0.f ? v : 0.f;
    }
}

// layer 3: BN + ReLU + write h + segment-sum into gemb
__global__ __launch_bounds__(256) void bn_relu_seg_kernel(float* __restrict__ h,
                                                          const float* __restrict__ stats,
                                                          const float* __restrict__ gamma,
                                                          const float* __restrict__ beta,
                                                          const int* __restrict__ batch,
                                                          float* __restrict__ gemb,
                                                          int n_nodes) {
    int g = blockIdx.x * blockDim.x + threadIdx.x;
    int f = g & 63;
    float mean = stats[f] * (1.0f / N_NODES);
    float var = stats[64 + f] * (1.0f / N_NODES) - mean * mean;
    float sc = gamma[f] * rsqrtf(var + EPS);
    float sh = beta[f] - mean * sc;
    int wave = g >> 6;
    int nwaves = (gridDim.x * blockDim.x) >> 6;
    for (int n = wave; n < n_nodes; n += nwaves) {
        size_t idx = (size_t)n * HID + f;
        float v = h[idx] * sc + sh;
        v = v > 0.f ? v : 0.f;
        h[idx] = v;
        atomicAdd(&gemb[(size_t)batch[n] * HID + f], v);
    }
}

__global__ __launch_bounds__(256) void final_kernel(const float* __restrict__ gemb,
                                                    const float* __restrict__ fcW,
                                                    const float* __restrict__ fcb,
                                                    float* __restrict__ out) {
    int g = blockIdx.x * blockDim.x + threadIdx.x;
    if (g >= N_GRAPHS * N_CLS) return;
    int gr = g >> 1, c = g & 1;
    float acc = fcb[c];
#pragma unroll
    for (int k = 0; k < HID; k++) acc += gemb[gr * HID + k] * fcW[k * N_CLS + c];
    out[g] = acc;
}

// ---------------- launch ----------------

extern "C" void kernel_launch(void* const* d_in, const int* in_sizes, int n_in,
                              void* d_out, int out_size, void* d_ws, size_t ws_size,
                              hipStream_t stream) {
    const float* x    = (const float*)d_in[0];
    const int*   ei   = (const int*)d_in[1];
    const int*   batch= (const int*)d_in[2];
    const float* ew   = (const float*)d_in[3];
    const float* W1   = (const float*)d_in[4];
    const float* b1   = (const float*)d_in[5];
    const float* W2   = (const float*)d_in[6];
    const float* b2   = (const float*)d_in[7];
    const float* W3   = (const float*)d_in[8];
    const float* b3   = (const float*)d_in[9];
    const float* g1   = (const float*)d_in[10];
    const float* bt1  = (const float*)d_in[11];
    const float* g2   = (const float*)d_in[12];
    const float* bt2  = (const float*)d_in[13];
    const float* g3   = (const float*)d_in[14];
    const float* bt3  = (const float*)d_in[15];
    const float* fcW  = (const float*)d_in[16];
    const float* fcb  = (const float*)d_in[17];

    const int* row = ei;
    const int* col = ei + N_EDGES;

    // d_out layout: out [2048*2] | node_embs [100000*64] | graph_emb [2048*64]
    float* out_head  = (float*)d_out;
    float* node_embs = out_head + N_GRAPHS * N_CLS;
    float* gemb      = node_embs + (size_t)N_NODES * HID;

    // ws layout
    float* xw     = (float*)d_ws;                       // 6.4M f
    float* dinv   = xw + (size_t)N_NODES * HID;         // 100K f
    float* stats  = dinv + N_NODES;                     // 128 f
    int*   ptrA   = (int*)(stats + 128);                // 100K i
    int*   cntA   = ptrA + N_NODES;                     // 100K i
    int*   curA   = cntA + N_NODES;                     // 100K i
    int*   bsum   = curA + N_NODES;                     // 512 i
    int*   srcs   = bsum + 512;                         // 1.6M i
    float* nrms   = (float*)(srcs + N_EDGES);           // 1.6M f

    const int B = 256;
    const int gN  = (N_NODES + B - 1) / B;   // per-node 1D
    const int NB1 = gN;                      // scan blocks (391)
    const int gGS = 1024;                    // grid-stride

    // ---- degree -> dinv ----
    fill_f32<<<gN, B, 0, stream>>>(dinv, 1.0f, N_NODES);
    deg_kernel<<<gGS, B, 0, stream>>>(col, ew, dinv, N_EDGES);
    dinv_kernel<<<gN, B, 0, stream>>>(dinv, N_NODES);

    // ---- CSR build (by dst col) ----
    hipMemsetAsync(cntA, 0, N_NODES * sizeof(int), stream);
    hist_kernel<<<gGS, B, 0, stream>>>(col, cntA, N_EDGES);
    blocksum_kernel<<<NB1, B, 0, stream>>>(cntA, bsum, N_NODES);
    topscan_kernel<<<1, 512, 0, stream>>>(bsum, NB1);
    blockscan_kernel<<<NB1, B, 0, stream>>>(cntA, bsum, ptrA, curA, N_NODES);
    scatter_edges_kernel<<<gGS, B, 0, stream>>>(row, col, ew, dinv, curA, srcs, nrms, N_EDGES);

    float* h = node_embs;  // per-layer activation; ends as h3 = node_embs output

    // ---- layer 1 (K = IN_F) ----
    gemm_kernel<IN_F><<<gGS, B, 0, stream>>>(x, W1, xw, N_NODES);
    hipMemsetAsync(stats, 0, 128 * sizeof(float), stream);
    gather_stats_kernel<<<gGS, B, 0, stream>>>(ptrA, cntA, srcs, nrms, xw, dinv, b1, h, stats, N_NODES);
    bn_relu_kernel<<<gGS, B, 0, stream>>>(h, stats, g1, bt1, N_NODES);

    // ---- layer 2 ----
    gemm_kernel<HID><<<gGS, B, 0, stream>>>(h, W2, xw, N_NODES);
    hipMemsetAsync(stats, 0, 128 * sizeof(float), stream);
    gather_stats_kernel<<<gGS, B, 0, stream>>>(ptrA, cntA, srcs, nrms, xw, dinv, b2, h, stats, N_NODES);
    bn_relu_kernel<<<gGS, B, 0, stream>>>(h, stats, g2, bt2, N_NODES);

    // ---- layer 3 (BN fused with segment-sum) ----
    gemm_kernel<HID><<<gGS, B, 0, stream>>>(h, W3, xw, N_NODES);
    hipMemsetAsync(stats, 0, 128 * sizeof(float), stream);
    gather_stats_kernel<<<gGS, B, 0, stream>>>(ptrA, cntA, srcs, nrms, xw, dinv, b3, h, stats, N_NODES);
    hipMemsetAsync(gemb, 0, (size_t)N_GRAPHS * HID * sizeof(float), stream);
    bn_relu_seg_kernel<<<gGS, B, 0, stream>>>(h, stats, g3, bt3, batch, gemb, N_NODES);

    // ---- readout ----
    final_kernel<<<(N_GRAPHS * N_CLS + B - 1) / B, B, 0, stream>>>(gemb, fcW, fcb, out_head);
}

// Round 3
// 954.516 us; speedup vs baseline: 1.5997x; 1.1370x over previous
//
#include <hip/hip_runtime.h>

#define N_NODES 100000
#define N_EDGES 1600000
#define N_GRAPHS 2048
#define HID 64
#define IN_F 14
#define N_CLS 2
#define EPS 1e-5f

typedef _Float16 half_t;

// ---------------- small utility kernels ----------------

__global__ __launch_bounds__(256) void fill_f32(float* p, float v, int n) {
    int i = blockIdx.x * blockDim.x + threadIdx.x;
    if (i < n) p[i] = v;
}

// deg[col[e]] += w[e]  (self-loop "+1" pre-filled by fill_f32)
__global__ __launch_bounds__(256) void deg_kernel(const int* __restrict__ col,
                                                  const float* __restrict__ w,
                                                  float* __restrict__ deg, int E) {
    int stride = gridDim.x * blockDim.x;
    for (int e = blockIdx.x * blockDim.x + threadIdx.x; e < E; e += stride)
        atomicAdd(&deg[col[e]], w[e]);
}

__global__ __launch_bounds__(256) void dinv_kernel(float* __restrict__ deg, int n) {
    int i = blockIdx.x * blockDim.x + threadIdx.x;
    if (i < n) deg[i] = rsqrtf(deg[i]);
}

// ---------------- CSR build (counting sort by dst) ----------------

__global__ __launch_bounds__(256) void hist_kernel(const int* __restrict__ col,
                                                   int* __restrict__ cnt, int E) {
    int stride = gridDim.x * blockDim.x;
    for (int e = blockIdx.x * blockDim.x + threadIdx.x; e < E; e += stride)
        atomicAdd(&cnt[col[e]], 1);
}

__global__ __launch_bounds__(256) void blocksum_kernel(const int* __restrict__ cnt,
                                                       int* __restrict__ bsum, int n) {
    __shared__ int ls[256];
    int i = blockIdx.x * 256 + threadIdx.x;
    ls[threadIdx.x] = (i < n) ? cnt[i] : 0;
    __syncthreads();
    for (int off = 128; off > 0; off >>= 1) {
        if (threadIdx.x < off) ls[threadIdx.x] += ls[threadIdx.x + off];
        __syncthreads();
    }
    if (threadIdx.x == 0) bsum[blockIdx.x] = ls[0];
}

__global__ __launch_bounds__(512) void topscan_kernel(int* __restrict__ bsum, int nb) {
    __shared__ int ls[512];
    int t = threadIdx.x;
    int v = (t < nb) ? bsum[t] : 0;
    ls[t] = v;
    __syncthreads();
    for (int off = 1; off < 512; off <<= 1) {
        int x = ls[t];
        if (t >= off) x += ls[t - off];
        __syncthreads();
        ls[t] = x;
        __syncthreads();
    }
    if (t < nb) bsum[t] = ls[t] - v;  // exclusive
}

__global__ __launch_bounds__(256) void blockscan_kernel(const int* __restrict__ cnt,
                                                        const int* __restrict__ bsum,
                                                        int* __restrict__ ptr,
                                                        int* __restrict__ cursor, int n) {
    __shared__ int ls[256];
    int i = blockIdx.x * 256 + threadIdx.x;
    int v = (i < n) ? cnt[i] : 0;
    ls[threadIdx.x] = v;
    __syncthreads();
    for (int off = 1; off < 256; off <<= 1) {
        int x = ls[threadIdx.x];
        if (threadIdx.x >= off) x += ls[threadIdx.x - off];
        __syncthreads();
        ls[threadIdx.x] = x;
        __syncthreads();
    }
    if (i < n) {
        int excl = ls[threadIdx.x] - v + bsum[blockIdx.x];
        ptr[i] = excl;
        cursor[i] = excl;
    }
}

__global__ __launch_bounds__(256) void scatter_edges_kernel(const int* __restrict__ row,
                                                            const int* __restrict__ col,
                                                            const float* __restrict__ w,
                                                            const float* __restrict__ dinv,
                                                            int* __restrict__ cursor,
                                                            int* __restrict__ srcs,
                                                            float* __restrict__ nrms, int E) {
    int stride = gridDim.x * blockDim.x;
    for (int e = blockIdx.x * blockDim.x + threadIdx.x; e < E; e += stride) {
        int r = row[e], c = col[e];
        int pos = atomicAdd(&cursor[c], 1);
        srcs[pos] = r;
        nrms[pos] = dinv[r] * w[e] * dinv[c];
    }
}

// ---------------- GEMM: xw_h = h @ W  (plain, layer 1) ----------------

template <int K>
__global__ __launch_bounds__(256) void gemm_kernel(const float* __restrict__ h,
                                                   const float* __restrict__ W,
                                                   half_t* __restrict__ xw, int n_nodes) {
    int f = threadIdx.x & 63;
    float wcol[K];
#pragma unroll
    for (int k = 0; k < K; k++) wcol[k] = W[k * HID + f];
    int wave = (blockIdx.x * blockDim.x + threadIdx.x) >> 6;
    int nwaves = (gridDim.x * blockDim.x) >> 6;
    for (int n = wave; n < n_nodes; n += nwaves) {
        const float* hr = h + (size_t)n * K;
        float acc = 0.f;
#pragma unroll
        for (int k = 0; k < K; k++) acc += hr[k] * wcol[k];
        xw[(size_t)n * HID + f] = (half_t)acc;
    }
}

// ---------------- GEMM with fused BN+ReLU on the input read ----------------
// xw_h = relu(bn(h_raw)) @ W   (h_raw is pre-BN; stats from previous gather)

__global__ __launch_bounds__(256) void gemm_bn_kernel(const float* __restrict__ h,
                                                      const float* __restrict__ W,
                                                      const float* __restrict__ stats,
                                                      const float* __restrict__ gamma,
                                                      const float* __restrict__ beta,
                                                      half_t* __restrict__ xw, int n_nodes) {
    __shared__ float sc_s[HID], sh_s[HID];
    int f = threadIdx.x & 63;
    if (threadIdx.x < 64) {
        float mean = stats[threadIdx.x] * (1.0f / N_NODES);
        float var = stats[64 + threadIdx.x] * (1.0f / N_NODES) - mean * mean;
        float sc = gamma[threadIdx.x] * rsqrtf(var + EPS);
        sc_s[threadIdx.x] = sc;
        sh_s[threadIdx.x] = beta[threadIdx.x] - mean * sc;
    }
    float wcol[HID];
#pragma unroll
    for (int k = 0; k < HID; k++) wcol[k] = W[k * HID + f];
    __syncthreads();
    int wave = (blockIdx.x * blockDim.x + threadIdx.x) >> 6;
    int nwaves = (gridDim.x * blockDim.x) >> 6;
    for (int n = wave; n < n_nodes; n += nwaves) {
        const float* hr = h + (size_t)n * HID;
        float acc = 0.f;
#pragma unroll
        for (int k = 0; k < HID; k++) {
            float v = hr[k] * sc_s[k] + sh_s[k];
            v = fmaxf(v, 0.f);
            acc += v * wcol[k];
        }
        xw[(size_t)n * HID + f] = (half_t)acc;
    }
}

// ---------------- fused CSR gather + self-loop + bias + BN stats ----------------
// wave per dst node (lane = feature); 4 edges in flight per iteration (MLP)
__global__ __launch_bounds__(256) void gather_stats_kernel(const int* __restrict__ ptr,
                                                           const int* __restrict__ cnt,
                                                           const int* __restrict__ srcs,
                                                           const float* __restrict__ nrms,
                                                           const half_t* __restrict__ xw,
                                                           const float* __restrict__ dinv,
                                                           const float* __restrict__ b,
                                                           float* __restrict__ h,
                                                           float* __restrict__ stats,
                                                           int n_nodes) {
    int g = blockIdx.x * blockDim.x + threadIdx.x;
    int f = g & 63;
    int lane = threadIdx.x & 63;
    int wave = g >> 6;
    int nwaves = (gridDim.x * blockDim.x) >> 6;
    float bf = b[f];
    float s = 0.f, s2 = 0.f;
    for (int n = wave; n < n_nodes; n += nwaves) {
        int beg = ptr[n];
        int c = cnt[n];
        float a0 = 0.f, a1 = 0.f, a2 = 0.f, a3 = 0.f;
        for (int j0 = 0; j0 < c; j0 += 64) {
            int m = c - j0;
            if (m > 64) m = 64;
            int sv = 0;
            float nv = 0.f;
            if (lane < m) {
                sv = srcs[beg + j0 + lane];
                nv = nrms[beg + j0 + lane];
            }
            int j = 0;
            for (; j + 4 <= m; j += 4) {
                int e0 = __shfl(sv, j), e1 = __shfl(sv, j + 1);
                int e2 = __shfl(sv, j + 2), e3 = __shfl(sv, j + 3);
                float w0 = __shfl(nv, j), w1 = __shfl(nv, j + 1);
                float w2 = __shfl(nv, j + 2), w3 = __shfl(nv, j + 3);
                float x0 = (float)xw[(size_t)e0 * HID + f];
                float x1 = (float)xw[(size_t)e1 * HID + f];
                float x2 = (float)xw[(size_t)e2 * HID + f];
                float x3 = (float)xw[(size_t)e3 * HID + f];
                a0 += w0 * x0;
                a1 += w1 * x1;
                a2 += w2 * x2;
                a3 += w3 * x3;
            }
            for (; j < m; j++) {
                int ej = __shfl(sv, j);
                float wj = __shfl(nv, j);
                a0 += wj * (float)xw[(size_t)ej * HID + f];
            }
        }
        float di = dinv[n];
        float v = ((a0 + a1) + (a2 + a3)) + di * di * (float)xw[(size_t)n * HID + f] + bf;
        h[(size_t)n * HID + f] = v;
        s += v;
        s2 += v * v;
    }
    __shared__ float ls[256], ls2[256];
    ls[threadIdx.x] = s;
    ls2[threadIdx.x] = s2;
    __syncthreads();
    if (threadIdx.x < 64) {
        float a = ls[threadIdx.x] + ls[threadIdx.x + 64] + ls[threadIdx.x + 128] + ls[threadIdx.x + 192];
        float a2 = ls2[threadIdx.x] + ls2[threadIdx.x + 64] + ls2[threadIdx.x + 128] + ls2[threadIdx.x + 192];
        atomicAdd(&stats[threadIdx.x], a);
        atomicAdd(&stats[64 + threadIdx.x], a2);
    }
}

// ---------------- layer 3: BN + ReLU + write node_embs + segment-sum ----------------
// wave handles a CONTIGUOUS node chunk; batch is sorted, so accumulate per-graph
// partials in registers and flush one atomic per graph transition.
__global__ __launch_bounds__(256) void bn_relu_seg_kernel(float* __restrict__ h,
                                                          const float* __restrict__ stats,
                                                          const float* __restrict__ gamma,
                                                          const float* __restrict__ beta,
                                                          const int* __restrict__ batch,
                                                          float* __restrict__ gemb,
                                                          int n_nodes) {
    int g = blockIdx.x * blockDim.x + threadIdx.x;
    int f = g & 63;
    int wave = g >> 6;
    int nwaves = (gridDim.x * blockDim.x) >> 6;
    int chunk = (n_nodes + nwaves - 1) / nwaves;
    int n0 = wave * chunk;
    int n1 = n0 + chunk;
    if (n1 > n_nodes) n1 = n_nodes;
    if (n0 >= n_nodes) return;
    float mean = stats[f] * (1.0f / N_NODES);
    float var = stats[64 + f] * (1.0f / N_NODES) - mean * mean;
    float sc = gamma[f] * rsqrtf(var + EPS);
    float sh = beta[f] - mean * sc;
    int curg = batch[n0];
    float racc = 0.f;
    for (int n = n0; n < n1; n++) {
        int bg = batch[n];
        if (bg != curg) {
            atomicAdd(&gemb[(size_t)curg * HID + f], racc);
            racc = 0.f;
            curg = bg;
        }
        size_t idx = (size_t)n * HID + f;
        float v = h[idx] * sc + sh;
        v = fmaxf(v, 0.f);
        h[idx] = v;
        racc += v;
    }
    atomicAdd(&gemb[(size_t)curg * HID + f], racc);
}

__global__ __launch_bounds__(256) void final_kernel(const float* __restrict__ gemb,
                                                    const float* __restrict__ fcW,
                                                    const float* __restrict__ fcb,
                                                    float* __restrict__ out) {
    int g = blockIdx.x * blockDim.x + threadIdx.x;
    if (g >= N_GRAPHS * N_CLS) return;
    int gr = g >> 1, c = g & 1;
    float acc = fcb[c];
#pragma unroll
    for (int k = 0; k < HID; k++) acc += gemb[gr * HID + k] * fcW[k * N_CLS + c];
    out[g] = acc;
}

// ---------------- launch ----------------

extern "C" void kernel_launch(void* const* d_in, const int* in_sizes, int n_in,
                              void* d_out, int out_size, void* d_ws, size_t ws_size,
                              hipStream_t stream) {
    const float* x    = (const float*)d_in[0];
    const int*   ei   = (const int*)d_in[1];
    const int*   batch= (const int*)d_in[2];
    const float* ew   = (const float*)d_in[3];
    const float* W1   = (const float*)d_in[4];
    const float* b1   = (const float*)d_in[5];
    const float* W2   = (const float*)d_in[6];
    const float* b2   = (const float*)d_in[7];
    const float* W3   = (const float*)d_in[8];
    const float* b3   = (const float*)d_in[9];
    const float* g1   = (const float*)d_in[10];
    const float* bt1  = (const float*)d_in[11];
    const float* g2   = (const float*)d_in[12];
    const float* bt2  = (const float*)d_in[13];
    const float* g3   = (const float*)d_in[14];
    const float* bt3  = (const float*)d_in[15];
    const float* fcW  = (const float*)d_in[16];
    const float* fcb  = (const float*)d_in[17];

    const int* row = ei;
    const int* col = ei + N_EDGES;

    // d_out layout: out [2048*2] | node_embs [100000*64] | graph_emb [2048*64]
    float* out_head  = (float*)d_out;
    float* node_embs = out_head + N_GRAPHS * N_CLS;
    float* gemb      = node_embs + (size_t)N_NODES * HID;

    // ws layout
    half_t* xwh  = (half_t*)d_ws;                        // 6.4M halves (12.8 MB)
    float* dinv  = (float*)(xwh + (size_t)N_NODES * HID);// 100K f
    float* stats = dinv + N_NODES;                       // 128 f
    int*   ptrA  = (int*)(stats + 128);                  // 100K i
    int*   cntA  = ptrA + N_NODES;                       // 100K i
    int*   curA  = cntA + N_NODES;                       // 100K i
    int*   bsum  = curA + N_NODES;                       // 512 i
    int*   srcs  = bsum + 512;                           // 1.6M i
    float* nrms  = (float*)(srcs + N_EDGES);             // 1.6M f

    const int B = 256;
    const int gN  = (N_NODES + B - 1) / B;   // per-node 1D
    const int NB1 = gN;                      // scan blocks (391)
    const int gGS = 1024;                    // grid-stride
    const int gGA = 2048;                    // gather (32 waves/CU)

    // ---- degree -> dinv ----
    fill_f32<<<gN, B, 0, stream>>>(dinv, 1.0f, N_NODES);
    deg_kernel<<<gGS, B, 0, stream>>>(col, ew, dinv, N_EDGES);
    dinv_kernel<<<gN, B, 0, stream>>>(dinv, N_NODES);

    // ---- CSR build (by dst col) ----
    hipMemsetAsync(cntA, 0, N_NODES * sizeof(int), stream);
    hist_kernel<<<gGS, B, 0, stream>>>(col, cntA, N_EDGES);
    blocksum_kernel<<<NB1, B, 0, stream>>>(cntA, bsum, N_NODES);
    topscan_kernel<<<1, 512, 0, stream>>>(bsum, NB1);
    blockscan_kernel<<<NB1, B, 0, stream>>>(cntA, bsum, ptrA, curA, N_NODES);
    scatter_edges_kernel<<<gGS, B, 0, stream>>>(row, col, ew, dinv, curA, srcs, nrms, N_EDGES);

    float* h = node_embs;  // raw (pre-BN) activation per layer; ends as h3 output

    // ---- layer 1 ----
    gemm_kernel<IN_F><<<gGS, B, 0, stream>>>(x, W1, xwh, N_NODES);
    hipMemsetAsync(stats, 0, 128 * sizeof(float), stream);
    gather_stats_kernel<<<gGA, B, 0, stream>>>(ptrA, cntA, srcs, nrms, xwh, dinv, b1, h, stats, N_NODES);

    // ---- layer 2 (BN1+ReLU fused into GEMM read) ----
    gemm_bn_kernel<<<gGS, B, 0, stream>>>(h, W2, stats, g1, bt1, xwh, N_NODES);
    hipMemsetAsync(stats, 0, 128 * sizeof(float), stream);
    gather_stats_kernel<<<gGA, B, 0, stream>>>(ptrA, cntA, srcs, nrms, xwh, dinv, b2, h, stats, N_NODES);

    // ---- layer 3 (BN2+ReLU fused into GEMM read) ----
    gemm_bn_kernel<<<gGS, B, 0, stream>>>(h, W3, stats, g2, bt2, xwh, N_NODES);
    hipMemsetAsync(stats, 0, 128 * sizeof(float), stream);
    gather_stats_kernel<<<gGA, B, 0, stream>>>(ptrA, cntA, srcs, nrms, xwh, dinv, b3, h, stats, N_NODES);

    // ---- BN3 + ReLU + node_embs + segment-sum ----
    hipMemsetAsync(gemb, 0, (size_t)N_GRAPHS * HID * sizeof(float), stream);
    bn_relu_seg_kernel<<<gGS, B, 0, stream>>>(h, stats, g3, bt3, batch, gemb, N_NODES);

    // ---- readout ----
    final_kernel<<<(N_GRAPHS * N_CLS + B - 1) / B, B, 0, stream>>>(gemb, fcW, fcb, out_head);
}

// Round 4
// 688.157 us; speedup vs baseline: 2.2189x; 1.3871x over previous
//
#include <hip/hip_runtime.h>

#define N_NODES 100000
#define N_EDGES 1600000
#define N_GRAPHS 2048
#define HID 64
#define IN_F 14
#define N_CLS 2
#define EPS 1e-5f

typedef _Float16 half_t;
typedef _Float16 half8 __attribute__((ext_vector_type(8)));
typedef float f32x4 __attribute__((ext_vector_type(4)));

// ---------------- small utility kernels ----------------

__global__ __launch_bounds__(256) void fill_f32(float* p, float v, int n) {
    int i = blockIdx.x * blockDim.x + threadIdx.x;
    if (i < n) p[i] = v;
}

// fused: deg[col[e]] += w[e]  AND  cnt[col[e]] += 1  (one pass over edges)
__global__ __launch_bounds__(256) void deg_hist_kernel(const int* __restrict__ col,
                                                       const float* __restrict__ w,
                                                       float* __restrict__ deg,
                                                       int* __restrict__ cnt, int E) {
    int stride = gridDim.x * blockDim.x;
    for (int e = blockIdx.x * blockDim.x + threadIdx.x; e < E; e += stride) {
        int c = col[e];
        atomicAdd(&deg[c], w[e]);
        atomicAdd(&cnt[c], 1);
    }
}

__global__ __launch_bounds__(256) void dinv_kernel(float* __restrict__ deg, int n) {
    int i = blockIdx.x * blockDim.x + threadIdx.x;
    if (i < n) deg[i] = rsqrtf(deg[i]);
}

// ---------------- CSR build (counting sort by dst) ----------------

__global__ __launch_bounds__(256) void blocksum_kernel(const int* __restrict__ cnt,
                                                       int* __restrict__ bsum, int n) {
    __shared__ int ls[256];
    int i = blockIdx.x * 256 + threadIdx.x;
    ls[threadIdx.x] = (i < n) ? cnt[i] : 0;
    __syncthreads();
    for (int off = 128; off > 0; off >>= 1) {
        if (threadIdx.x < off) ls[threadIdx.x] += ls[threadIdx.x + off];
        __syncthreads();
    }
    if (threadIdx.x == 0) bsum[blockIdx.x] = ls[0];
}

__global__ __launch_bounds__(512) void topscan_kernel(int* __restrict__ bsum, int nb) {
    __shared__ int ls[512];
    int t = threadIdx.x;
    int v = (t < nb) ? bsum[t] : 0;
    ls[t] = v;
    __syncthreads();
    for (int off = 1; off < 512; off <<= 1) {
        int x = ls[t];
        if (t >= off) x += ls[t - off];
        __syncthreads();
        ls[t] = x;
        __syncthreads();
    }
    if (t < nb) bsum[t] = ls[t] - v;  // exclusive
}

__global__ __launch_bounds__(256) void blockscan_kernel(const int* __restrict__ cnt,
                                                        const int* __restrict__ bsum,
                                                        int* __restrict__ ptr,
                                                        int* __restrict__ cursor, int n) {
    __shared__ int ls[256];
    int i = blockIdx.x * 256 + threadIdx.x;
    int v = (i < n) ? cnt[i] : 0;
    ls[threadIdx.x] = v;
    __syncthreads();
    for (int off = 1; off < 256; off <<= 1) {
        int x = ls[threadIdx.x];
        if (threadIdx.x >= off) x += ls[threadIdx.x - off];
        __syncthreads();
        ls[threadIdx.x] = x;
        __syncthreads();
    }
    if (i < n) {
        int excl = ls[threadIdx.x] - v + bsum[blockIdx.x];
        ptr[i] = excl;
        cursor[i] = excl;
    }
}

// permute edges into dst-sorted order; pack (src, norm) into int2
__global__ __launch_bounds__(256) void scatter_edges_kernel(const int* __restrict__ row,
                                                            const int* __restrict__ col,
                                                            const float* __restrict__ w,
                                                            const float* __restrict__ dinv,
                                                            int* __restrict__ cursor,
                                                            int2* __restrict__ edges, int E) {
    int stride = gridDim.x * blockDim.x;
    for (int e = blockIdx.x * blockDim.x + threadIdx.x; e < E; e += stride) {
        int r = row[e], c = col[e];
        int pos = atomicAdd(&cursor[c], 1);
        float nrm = dinv[r] * w[e] * dinv[c];
        edges[pos] = make_int2(r, __float_as_int(nrm));
    }
}

// ---------------- layer-1 GEMM (K=14, VALU fine) ----------------

template <int K>
__global__ __launch_bounds__(256) void gemm_kernel(const float* __restrict__ h,
                                                   const float* __restrict__ W,
                                                   half_t* __restrict__ xw, int n_nodes) {
    int f = threadIdx.x & 63;
    float wcol[K];
#pragma unroll
    for (int k = 0; k < K; k++) wcol[k] = W[k * HID + f];
    int wave = (blockIdx.x * blockDim.x + threadIdx.x) >> 6;
    int nwaves = (gridDim.x * blockDim.x) >> 6;
    for (int n = wave; n < n_nodes; n += nwaves) {
        const float* hr = h + (size_t)n * K;
        float acc = 0.f;
#pragma unroll
        for (int k = 0; k < K; k++) acc += hr[k] * wcol[k];
        xw[(size_t)n * HID + f] = (half_t)acc;
    }
}

// ---------------- MFMA GEMM with fused BN+ReLU on input ----------------
// xw = relu(bn(h)) @ W, fp16 MFMA 16x16x32.
// A layout: m=lane&15, k=quad*8+j (verified m120). C/D: col=lane&15, row=quad*4+reg (m89/91).
// Requires n_nodes % 16 == 0 (100000 = 6250*16).
__global__ __launch_bounds__(256) void gemm_bn_mfma_kernel(const float* __restrict__ h,
                                                           const float* __restrict__ W,
                                                           const float* __restrict__ stats,
                                                           const float* __restrict__ gamma,
                                                           const float* __restrict__ beta,
                                                           half_t* __restrict__ xw, int n_nodes) {
    __shared__ float sc_s[HID], sh_s[HID];
    if (threadIdx.x < 64) {
        float mean = stats[threadIdx.x] * (1.0f / N_NODES);
        float var = stats[64 + threadIdx.x] * (1.0f / N_NODES) - mean * mean;
        float sc = gamma[threadIdx.x] * rsqrtf(var + EPS);
        sc_s[threadIdx.x] = sc;
        sh_s[threadIdx.x] = beta[threadIdx.x] - mean * sc;
    }
    __syncthreads();
    int lane = threadIdx.x & 63;
    int col16 = lane & 15;
    int quad = lane >> 4;

    // per-lane BN constants for the A fragment's k-slots
    float scA[2][8], shA[2][8];
#pragma unroll
    for (int kh = 0; kh < 2; kh++)
#pragma unroll
        for (int j = 0; j < 8; j++) {
            int k = kh * 32 + quad * 8 + j;
            scA[kh][j] = sc_s[k];
            shA[kh][j] = sh_s[k];
        }

    // B fragments: B[k][n], n=lane&15, k=quad*8+j (+32 for second half); 4 n-tiles
    half8 bfrag[4][2];
#pragma unroll
    for (int t = 0; t < 4; t++)
#pragma unroll
        for (int kh = 0; kh < 2; kh++)
#pragma unroll
            for (int j = 0; j < 8; j++) {
                int k = kh * 32 + quad * 8 + j;
                bfrag[t][kh][j] = (half_t)W[k * HID + t * 16 + col16];
            }

    int wave = (blockIdx.x * blockDim.x + threadIdx.x) >> 6;
    int nwaves = (gridDim.x * blockDim.x) >> 6;
    int ntiles = n_nodes >> 4;
    for (int tIdx = wave; tIdx < ntiles; tIdx += nwaves) {
        int n0 = tIdx << 4;
        const float* hr = h + (size_t)(n0 + col16) * HID + quad * 8;
        half8 afrag[2];
#pragma unroll
        for (int kh = 0; kh < 2; kh++) {
            float4 p0 = *(const float4*)(hr + kh * 32);
            float4 p1 = *(const float4*)(hr + kh * 32 + 4);
            float fv[8] = {p0.x, p0.y, p0.z, p0.w, p1.x, p1.y, p1.z, p1.w};
#pragma unroll
            for (int j = 0; j < 8; j++) {
                float v = fv[j] * scA[kh][j] + shA[kh][j];
                afrag[kh][j] = (half_t)fmaxf(v, 0.f);
            }
        }
        f32x4 acc[4];
#pragma unroll
        for (int t = 0; t < 4; t++) {
            f32x4 z = {0.f, 0.f, 0.f, 0.f};
            acc[t] = __builtin_amdgcn_mfma_f32_16x16x32_f16(afrag[0], bfrag[t][0], z, 0, 0, 0);
            acc[t] = __builtin_amdgcn_mfma_f32_16x16x32_f16(afrag[1], bfrag[t][1], acc[t], 0, 0, 0);
        }
        half_t* xr = xw + (size_t)n0 * HID;
#pragma unroll
        for (int t = 0; t < 4; t++)
#pragma unroll
            for (int r = 0; r < 4; r++) {
                int rowi = quad * 4 + r;
                xr[(size_t)rowi * HID + t * 16 + col16] = (half_t)acc[t][r];
            }
    }
}

// ---------------- fused CSR gather + self-loop + bias + BN stats ----------------
// wave per dst node (lane = feature); 8 gathers in flight (MLP)
__global__ __launch_bounds__(256) void gather_stats_kernel(const int* __restrict__ ptr,
                                                           const int* __restrict__ cnt,
                                                           const int2* __restrict__ edges,
                                                           const half_t* __restrict__ xw,
                                                           const float* __restrict__ dinv,
                                                           const float* __restrict__ b,
                                                           float* __restrict__ h,
                                                           float* __restrict__ stats,
                                                           int n_nodes) {
    int g = blockIdx.x * blockDim.x + threadIdx.x;
    int f = g & 63;
    int lane = threadIdx.x & 63;
    int wave = g >> 6;
    int nwaves = (gridDim.x * blockDim.x) >> 6;
    float bf = b[f];
    float s = 0.f, s2 = 0.f;
    for (int n = wave; n < n_nodes; n += nwaves) {
        int beg = ptr[n];
        int c = cnt[n];
        float a0 = 0.f, a1 = 0.f, a2 = 0.f, a3 = 0.f;
        float a4 = 0.f, a5 = 0.f, a6 = 0.f, a7 = 0.f;
        for (int j0 = 0; j0 < c; j0 += 64) {
            int m = c - j0;
            if (m > 64) m = 64;
            int sv = 0;
            float nv = 0.f;
            if (lane < m) {
                int2 e = edges[beg + j0 + lane];
                sv = e.x;
                nv = __int_as_float(e.y);
            }
            int j = 0;
            for (; j + 8 <= m; j += 8) {
                int e0 = __shfl(sv, j),     e1 = __shfl(sv, j + 1);
                int e2 = __shfl(sv, j + 2), e3 = __shfl(sv, j + 3);
                int e4 = __shfl(sv, j + 4), e5 = __shfl(sv, j + 5);
                int e6 = __shfl(sv, j + 6), e7 = __shfl(sv, j + 7);
                float w0 = __shfl(nv, j),     w1 = __shfl(nv, j + 1);
                float w2 = __shfl(nv, j + 2), w3 = __shfl(nv, j + 3);
                float w4 = __shfl(nv, j + 4), w5 = __shfl(nv, j + 5);
                float w6 = __shfl(nv, j + 6), w7 = __shfl(nv, j + 7);
                float x0 = (float)xw[(size_t)e0 * HID + f];
                float x1 = (float)xw[(size_t)e1 * HID + f];
                float x2 = (float)xw[(size_t)e2 * HID + f];
                float x3 = (float)xw[(size_t)e3 * HID + f];
                float x4 = (float)xw[(size_t)e4 * HID + f];
                float x5 = (float)xw[(size_t)e5 * HID + f];
                float x6 = (float)xw[(size_t)e6 * HID + f];
                float x7 = (float)xw[(size_t)e7 * HID + f];
                a0 += w0 * x0; a1 += w1 * x1; a2 += w2 * x2; a3 += w3 * x3;
                a4 += w4 * x4; a5 += w5 * x5; a6 += w6 * x6; a7 += w7 * x7;
            }
            for (; j < m; j++) {
                int ej = __shfl(sv, j);
                float wj = __shfl(nv, j);
                a0 += wj * (float)xw[(size_t)ej * HID + f];
            }
        }
        float di = dinv[n];
        float v = (((a0 + a1) + (a2 + a3)) + ((a4 + a5) + (a6 + a7)))
                  + di * di * (float)xw[(size_t)n * HID + f] + bf;
        h[(size_t)n * HID + f] = v;
        s += v;
        s2 += v * v;
    }
    __shared__ float ls[256], ls2[256];
    ls[threadIdx.x] = s;
    ls2[threadIdx.x] = s2;
    __syncthreads();
    if (threadIdx.x < 64) {
        float a = ls[threadIdx.x] + ls[threadIdx.x + 64] + ls[threadIdx.x + 128] + ls[threadIdx.x + 192];
        float a2 = ls2[threadIdx.x] + ls2[threadIdx.x + 64] + ls2[threadIdx.x + 128] + ls2[threadIdx.x + 192];
        atomicAdd(&stats[threadIdx.x], a);
        atomicAdd(&stats[64 + threadIdx.x], a2);
    }
}

// ---------------- layer 3: BN + ReLU + write node_embs + segment-sum ----------------
__global__ __launch_bounds__(256) void bn_relu_seg_kernel(float* __restrict__ h,
                                                          const float* __restrict__ stats,
                                                          const float* __restrict__ gamma,
                                                          const float* __restrict__ beta,
                                                          const int* __restrict__ batch,
                                                          float* __restrict__ gemb,
                                                          int n_nodes) {
    int g = blockIdx.x * blockDim.x + threadIdx.x;
    int f = g & 63;
    int wave = g >> 6;
    int nwaves = (gridDim.x * blockDim.x) >> 6;
    int chunk = (n_nodes + nwaves - 1) / nwaves;
    int n0 = wave * chunk;
    int n1 = n0 + chunk;
    if (n1 > n_nodes) n1 = n_nodes;
    if (n0 >= n_nodes) return;
    float mean = stats[f] * (1.0f / N_NODES);
    float var = stats[64 + f] * (1.0f / N_NODES) - mean * mean;
    float sc = gamma[f] * rsqrtf(var + EPS);
    float sh = beta[f] - mean * sc;
    int curg = batch[n0];
    float racc = 0.f;
    for (int n = n0; n < n1; n++) {
        int bg = batch[n];
        if (bg != curg) {
            atomicAdd(&gemb[(size_t)curg * HID + f], racc);
            racc = 0.f;
            curg = bg;
        }
        size_t idx = (size_t)n * HID + f;
        float v = h[idx] * sc + sh;
        v = fmaxf(v, 0.f);
        h[idx] = v;
        racc += v;
    }
    atomicAdd(&gemb[(size_t)curg * HID + f], racc);
}

__global__ __launch_bounds__(256) void final_kernel(const float* __restrict__ gemb,
                                                    const float* __restrict__ fcW,
                                                    const float* __restrict__ fcb,
                                                    float* __restrict__ out) {
    int g = blockIdx.x * blockDim.x + threadIdx.x;
    if (g >= N_GRAPHS * N_CLS) return;
    int gr = g >> 1, c = g & 1;
    float acc = fcb[c];
#pragma unroll
    for (int k = 0; k < HID; k++) acc += gemb[gr * HID + k] * fcW[k * N_CLS + c];
    out[g] = acc;
}

// ---------------- launch ----------------

extern "C" void kernel_launch(void* const* d_in, const int* in_sizes, int n_in,
                              void* d_out, int out_size, void* d_ws, size_t ws_size,
                              hipStream_t stream) {
    const float* x    = (const float*)d_in[0];
    const int*   ei   = (const int*)d_in[1];
    const int*   batch= (const int*)d_in[2];
    const float* ew   = (const float*)d_in[3];
    const float* W1   = (const float*)d_in[4];
    const float* b1   = (const float*)d_in[5];
    const float* W2   = (const float*)d_in[6];
    const float* b2   = (const float*)d_in[7];
    const float* W3   = (const float*)d_in[8];
    const float* b3   = (const float*)d_in[9];
    const float* g1   = (const float*)d_in[10];
    const float* bt1  = (const float*)d_in[11];
    const float* g2   = (const float*)d_in[12];
    const float* bt2  = (const float*)d_in[13];
    const float* g3   = (const float*)d_in[14];
    const float* bt3  = (const float*)d_in[15];
    const float* fcW  = (const float*)d_in[16];
    const float* fcb  = (const float*)d_in[17];

    const int* row = ei;
    const int* col = ei + N_EDGES;

    // d_out layout: out [2048*2] | node_embs [100000*64] | graph_emb [2048*64]
    float* out_head  = (float*)d_out;
    float* node_embs = out_head + N_GRAPHS * N_CLS;
    float* gemb      = node_embs + (size_t)N_NODES * HID;

    // ws layout
    half_t* xwh  = (half_t*)d_ws;                        // 6.4M halves (12.8 MB)
    float* dinv  = (float*)(xwh + (size_t)N_NODES * HID);// 100K f
    float* stats = dinv + N_NODES;                       // 128 f
    int*   ptrA  = (int*)(stats + 128);                  // 100K i
    int*   cntA  = ptrA + N_NODES;                       // 100K i
    int*   curA  = cntA + N_NODES;                       // 100K i
    int*   bsum  = curA + N_NODES;                       // 512 i
    int2*  edges = (int2*)(bsum + 512);                  // 1.6M int2 (12.8 MB)

    const int B = 256;
    const int gN  = (N_NODES + B - 1) / B;   // per-node 1D
    const int NB1 = gN;                      // scan blocks (391)
    const int gGS = 1024;                    // grid-stride
    const int gGA = 2048;                    // gather (fills 8192 waves)

    // ---- degree + histogram (single edge pass) ----
    fill_f32<<<gN, B, 0, stream>>>(dinv, 1.0f, N_NODES);
    hipMemsetAsync(cntA, 0, N_NODES * sizeof(int), stream);
    deg_hist_kernel<<<gGS, B, 0, stream>>>(col, ew, dinv, cntA, N_EDGES);
    dinv_kernel<<<gN, B, 0, stream>>>(dinv, N_NODES);

    // ---- CSR build (by dst col) ----
    blocksum_kernel<<<NB1, B, 0, stream>>>(cntA, bsum, N_NODES);
    topscan_kernel<<<1, 512, 0, stream>>>(bsum, NB1);
    blockscan_kernel<<<NB1, B, 0, stream>>>(cntA, bsum, ptrA, curA, N_NODES);
    scatter_edges_kernel<<<gGS, B, 0, stream>>>(row, col, ew, dinv, curA, edges, N_EDGES);

    float* h = node_embs;  // raw (pre-BN) activation per layer; ends as h3 output

    // ---- layer 1 ----
    gemm_kernel<IN_F><<<gGS, B, 0, stream>>>(x, W1, xwh, N_NODES);
    hipMemsetAsync(stats, 0, 128 * sizeof(float), stream);
    gather_stats_kernel<<<gGA, B, 0, stream>>>(ptrA, cntA, edges, xwh, dinv, b1, h, stats, N_NODES);

    // ---- layer 2 (BN1+ReLU fused into MFMA GEMM) ----
    gemm_bn_mfma_kernel<<<gGS, B, 0, stream>>>(h, W2, stats, g1, bt1, xwh, N_NODES);
    hipMemsetAsync(stats, 0, 128 * sizeof(float), stream);
    gather_stats_kernel<<<gGA, B, 0, stream>>>(ptrA, cntA, edges, xwh, dinv, b2, h, stats, N_NODES);

    // ---- layer 3 (BN2+ReLU fused into MFMA GEMM) ----
    gemm_bn_mfma_kernel<<<gGS, B, 0, stream>>>(h, W3, stats, g2, bt2, xwh, N_NODES);
    hipMemsetAsync(stats, 0, 128 * sizeof(float), stream);
    gather_stats_kernel<<<gGA, B, 0, stream>>>(ptrA, cntA, edges, xwh, dinv, b3, h, stats, N_NODES);

    // ---- BN3 + ReLU + node_embs + segment-sum ----
    hipMemsetAsync(gemb, 0, (size_t)N_GRAPHS * HID * sizeof(float), stream);
    bn_relu_seg_kernel<<<gGS, B, 0, stream>>>(h, stats, g3, bt3, batch, gemb, N_NODES);

    // ---- readout ----
    final_kernel<<<(N_GRAPHS * N_CLS + B - 1) / B, B, 0, stream>>>(gemb, fcW, fcb, out_head);
}

// Round 5
// 503.526 us; speedup vs baseline: 3.0325x; 1.3667x over previous
//
#include <hip/hip_runtime.h>

#define N_NODES 100000
#define N_EDGES 1600000
#define N_GRAPHS 2048
#define HID 64
#define IN_F 14
#define N_CLS 2
#define EPS 1e-5f

typedef _Float16 half_t;
typedef _Float16 half8 __attribute__((ext_vector_type(8)));
typedef float f32x4 __attribute__((ext_vector_type(4)));

#define GSTRIDE ((size_t)N_NODES * 16)   // halves per feature-group plane

// ---------------- CSR build: one packed atomic per edge ----------------
// packed[c]: high 32 = fixed-point (w * 65536) sum, low 32 = count.
// atomicAdd's returned low half = this edge's rank within bin c.
__global__ __launch_bounds__(256) void hist_rank_kernel(const int* __restrict__ col,
                                                        const float* __restrict__ w,
                                                        unsigned long long* __restrict__ packed,
                                                        int* __restrict__ rank, int E) {
    int stride = gridDim.x * blockDim.x;
    for (int e = blockIdx.x * blockDim.x + threadIdx.x; e < E; e += stride) {
        int c = col[e];
        unsigned int fx = __float2uint_rn(w[e] * 65536.0f);
        unsigned long long old =
            atomicAdd(&packed[c], ((unsigned long long)fx << 32) | 1ull);
        rank[e] = (int)(old & 0xffffffffull);
    }
}

// dinv[n] = rsqrt(1 + wsum[n])
__global__ __launch_bounds__(256) void dinv_from_packed(const unsigned long long* __restrict__ packed,
                                                        float* __restrict__ dinv, int n) {
    int i = blockIdx.x * blockDim.x + threadIdx.x;
    if (i < n) {
        float wsum = (float)(packed[i] >> 32) * (1.0f / 65536.0f);
        dinv[i] = rsqrtf(1.0f + wsum);
    }
}

// ---- exclusive scan of counts (1024 bins per block, 4 per thread) ----

__global__ __launch_bounds__(256) void blocksum1024_kernel(const unsigned long long* __restrict__ packed,
                                                           int* __restrict__ bsum, int n) {
    __shared__ int ls[256];
    int base = blockIdx.x * 1024 + threadIdx.x * 4;
    int s = 0;
#pragma unroll
    for (int k = 0; k < 4; k++) {
        int i = base + k;
        if (i < n) s += (int)(packed[i] & 0xffffffffull);
    }
    ls[threadIdx.x] = s;
    __syncthreads();
    for (int off = 128; off > 0; off >>= 1) {
        if (threadIdx.x < off) ls[threadIdx.x] += ls[threadIdx.x + off];
        __syncthreads();
    }
    if (threadIdx.x == 0) bsum[blockIdx.x] = ls[0];
}

__global__ __launch_bounds__(512) void topscan_kernel(int* __restrict__ bsum, int nb) {
    __shared__ int ls[512];
    int t = threadIdx.x;
    int v = (t < nb) ? bsum[t] : 0;
    ls[t] = v;
    __syncthreads();
    for (int off = 1; off < 512; off <<= 1) {
        int x = ls[t];
        if (t >= off) x += ls[t - off];
        __syncthreads();
        ls[t] = x;
        __syncthreads();
    }
    if (t < nb) bsum[t] = ls[t] - v;  // exclusive
}

__global__ __launch_bounds__(256) void blockscan1024_kernel(const unsigned long long* __restrict__ packed,
                                                            const int* __restrict__ bsum,
                                                            int* __restrict__ ptr, int n, int E) {
    __shared__ int ls[256];
    int base = blockIdx.x * 1024 + threadIdx.x * 4;
    int c[4];
    int s = 0;
#pragma unroll
    for (int k = 0; k < 4; k++) {
        int i = base + k;
        c[k] = (i < n) ? (int)(packed[i] & 0xffffffffull) : 0;
        s += c[k];
    }
    ls[threadIdx.x] = s;
    __syncthreads();
    for (int off = 1; off < 256; off <<= 1) {
        int x = ls[threadIdx.x];
        if (threadIdx.x >= off) x += ls[threadIdx.x - off];
        __syncthreads();
        ls[threadIdx.x] = x;
        __syncthreads();
    }
    int run = ls[threadIdx.x] - s + bsum[blockIdx.x];
#pragma unroll
    for (int k = 0; k < 4; k++) {
        int i = base + k;
        if (i < n) ptr[i] = run;
        run += c[k];
    }
    if (blockIdx.x == 0 && threadIdx.x == 0) ptr[n] = E;
}

// atomic-free permute: pos = ptr[c] + rank[e]
__global__ __launch_bounds__(256) void permute_kernel(const int* __restrict__ row,
                                                      const int* __restrict__ col,
                                                      const float* __restrict__ w,
                                                      const float* __restrict__ dinv,
                                                      const int* __restrict__ ptr,
                                                      const int* __restrict__ rank,
                                                      int2* __restrict__ edges, int E) {
    int stride = gridDim.x * blockDim.x;
    for (int e = blockIdx.x * blockDim.x + threadIdx.x; e < E; e += stride) {
        int r = row[e], c = col[e];
        int pos = ptr[c] + rank[e];
        float nrm = dinv[r] * w[e] * dinv[c];
        edges[pos] = make_int2(r, __float_as_int(nrm));
    }
}

// ---------------- layer-1 GEMM (K=14, VALU), grouped store ----------------

template <int K>
__global__ __launch_bounds__(256) void gemm_kernel(const float* __restrict__ h,
                                                   const float* __restrict__ W,
                                                   half_t* __restrict__ xw, int n_nodes) {
    int f = threadIdx.x & 63;
    float wcol[K];
#pragma unroll
    for (int k = 0; k < K; k++) wcol[k] = W[k * HID + f];
    half_t* xg = xw + (size_t)(f >> 4) * GSTRIDE + (f & 15);
    int wave = (blockIdx.x * blockDim.x + threadIdx.x) >> 6;
    int nwaves = (gridDim.x * blockDim.x) >> 6;
    for (int n = wave; n < n_nodes; n += nwaves) {
        const float* hr = h + (size_t)n * K;
        float acc = 0.f;
#pragma unroll
        for (int k = 0; k < K; k++) acc += hr[k] * wcol[k];
        xg[(size_t)n * 16] = (half_t)acc;
    }
}

// ---------------- MFMA GEMM with fused BN+ReLU, grouped store ----------------
__global__ __launch_bounds__(256) void gemm_bn_mfma_kernel(const float* __restrict__ h,
                                                           const float* __restrict__ W,
                                                           const float* __restrict__ stats,
                                                           const float* __restrict__ gamma,
                                                           const float* __restrict__ beta,
                                                           half_t* __restrict__ xw, int n_nodes) {
    __shared__ float sc_s[HID], sh_s[HID];
    if (threadIdx.x < 64) {
        float mean = stats[threadIdx.x] * (1.0f / N_NODES);
        float var = stats[64 + threadIdx.x] * (1.0f / N_NODES) - mean * mean;
        float sc = gamma[threadIdx.x] * rsqrtf(var + EPS);
        sc_s[threadIdx.x] = sc;
        sh_s[threadIdx.x] = beta[threadIdx.x] - mean * sc;
    }
    __syncthreads();
    int lane = threadIdx.x & 63;
    int col16 = lane & 15;
    int quad = lane >> 4;

    float scA[2][8], shA[2][8];
#pragma unroll
    for (int kh = 0; kh < 2; kh++)
#pragma unroll
        for (int j = 0; j < 8; j++) {
            int k = kh * 32 + quad * 8 + j;
            scA[kh][j] = sc_s[k];
            shA[kh][j] = sh_s[k];
        }

    half8 bfrag[4][2];
#pragma unroll
    for (int t = 0; t < 4; t++)
#pragma unroll
        for (int kh = 0; kh < 2; kh++)
#pragma unroll
            for (int j = 0; j < 8; j++) {
                int k = kh * 32 + quad * 8 + j;
                bfrag[t][kh][j] = (half_t)W[k * HID + t * 16 + col16];
            }

    int wave = (blockIdx.x * blockDim.x + threadIdx.x) >> 6;
    int nwaves = (gridDim.x * blockDim.x) >> 6;
    int ntiles = n_nodes >> 4;
    for (int tIdx = wave; tIdx < ntiles; tIdx += nwaves) {
        int n0 = tIdx << 4;
        const float* hr = h + (size_t)(n0 + col16) * HID + quad * 8;
        half8 afrag[2];
#pragma unroll
        for (int kh = 0; kh < 2; kh++) {
            float4 p0 = *(const float4*)(hr + kh * 32);
            float4 p1 = *(const float4*)(hr + kh * 32 + 4);
            float fv[8] = {p0.x, p0.y, p0.z, p0.w, p1.x, p1.y, p1.z, p1.w};
#pragma unroll
            for (int j = 0; j < 8; j++) {
                float v = fv[j] * scA[kh][j] + shA[kh][j];
                afrag[kh][j] = (half_t)fmaxf(v, 0.f);
            }
        }
        f32x4 acc[4];
#pragma unroll
        for (int t = 0; t < 4; t++) {
            f32x4 z = {0.f, 0.f, 0.f, 0.f};
            acc[t] = __builtin_amdgcn_mfma_f32_16x16x32_f16(afrag[0], bfrag[t][0], z, 0, 0, 0);
            acc[t] = __builtin_amdgcn_mfma_f32_16x16x32_f16(afrag[1], bfrag[t][1], acc[t], 0, 0, 0);
        }
#pragma unroll
        for (int t = 0; t < 4; t++) {
            half_t* xg = xw + (size_t)t * GSTRIDE;
#pragma unroll
            for (int r = 0; r < 4; r++) {
                int rowi = n0 + quad * 4 + r;
                xg[(size_t)rowi * 16 + col16] = (half_t)acc[t][r];
            }
        }
    }
}

// ---------------- feature-grouped CSR gather + self-loop + bias + BN stats ----
// blockIdx%8 -> XCD pair heuristic: group g = (blockIdx%8)>>1 touches only its
// 3.2 MB xw plane (L2-resident). Quad of a wave = (node, 16 features).
__global__ __launch_bounds__(256) void gather_stats_kernel(const int* __restrict__ ptr,
                                                           const int2* __restrict__ edges,
                                                           const half_t* __restrict__ xw,
                                                           const float* __restrict__ dinv,
                                                           const float* __restrict__ b,
                                                           float* __restrict__ h,
                                                           float* __restrict__ stats,
                                                           int n_nodes) {
    int g = (blockIdx.x & 7) >> 1;                           // feature group 0..3
    int grank = ((blockIdx.x >> 3) << 1) | (blockIdx.x & 1); // rank within group
    int lane16 = threadIdx.x & 15;
    int quadLocal = threadIdx.x >> 4;                        // 0..15
    int quadId = grank * 16 + quadLocal;
    int nquads = (gridDim.x >> 2) * 16;

    const half_t* xg = xw + (size_t)g * GSTRIDE;
    int f = g * 16 + lane16;
    float bf = b[f];
    int base = ((threadIdx.x & 63) >> 4) * 16;               // quad's shfl window

    float s = 0.f, s2 = 0.f;
    for (int n = quadId; n < n_nodes; n += nquads) {
        int beg = ptr[n];
        int c = ptr[n + 1] - beg;
        float a0 = 0.f, a1 = 0.f, a2 = 0.f, a3 = 0.f;
        for (int j0 = 0; j0 < c; j0 += 16) {
            int m = c - j0;
            if (m > 16) m = 16;
            int sv = 0;
            float nv = 0.f;
            if (lane16 < m) {
                int2 e = edges[beg + j0 + lane16];
                sv = e.x;
                nv = __int_as_float(e.y);
            }
            int j = 0;
            for (; j + 4 <= m; j += 4) {
                int e0 = __shfl(sv, base + j),     e1 = __shfl(sv, base + j + 1);
                int e2 = __shfl(sv, base + j + 2), e3 = __shfl(sv, base + j + 3);
                float w0 = __shfl(nv, base + j),     w1 = __shfl(nv, base + j + 1);
                float w2 = __shfl(nv, base + j + 2), w3 = __shfl(nv, base + j + 3);
                float x0 = (float)xg[(size_t)e0 * 16 + lane16];
                float x1 = (float)xg[(size_t)e1 * 16 + lane16];
                float x2 = (float)xg[(size_t)e2 * 16 + lane16];
                float x3 = (float)xg[(size_t)e3 * 16 + lane16];
                a0 += w0 * x0; a1 += w1 * x1; a2 += w2 * x2; a3 += w3 * x3;
            }
            if (j < m) {
                int e0 = __shfl(sv, base + j);
                float w0 = __shfl(nv, base + j);
                a1 += w0 * (float)xg[(size_t)e0 * 16 + lane16];
            }
            if (j + 1 < m) {
                int e0 = __shfl(sv, base + j + 1);
                float w0 = __shfl(nv, base + j + 1);
                a2 += w0 * (float)xg[(size_t)e0 * 16 + lane16];
            }
            if (j + 2 < m) {
                int e0 = __shfl(sv, base + j + 2);
                float w0 = __shfl(nv, base + j + 2);
                a3 += w0 * (float)xg[(size_t)e0 * 16 + lane16];
            }
        }
        float di = dinv[n];
        float v = ((a0 + a1) + (a2 + a3)) + di * di * (float)xg[(size_t)n * 16 + lane16] + bf;
        h[(size_t)n * HID + f] = v;
        s += v;
        s2 += v * v;
    }
    __shared__ float ls[256], ls2[256];
    ls[threadIdx.x] = s;
    ls2[threadIdx.x] = s2;
    __syncthreads();
    if (threadIdx.x < 16) {
        float a = 0.f, aa = 0.f;
#pragma unroll
        for (int k = 0; k < 16; k++) {
            a += ls[k * 16 + threadIdx.x];
            aa += ls2[k * 16 + threadIdx.x];
        }
        atomicAdd(&stats[g * 16 + threadIdx.x], a);
        atomicAdd(&stats[64 + g * 16 + threadIdx.x], aa);
    }
}

// ---------------- layer 3: BN + ReLU + write node_embs + segment-sum --------
__global__ __launch_bounds__(256) void bn_relu_seg_kernel(float* __restrict__ h,
                                                          const float* __restrict__ stats,
                                                          const float* __restrict__ gamma,
                                                          const float* __restrict__ beta,
                                                          const int* __restrict__ batch,
                                                          float* __restrict__ gemb,
                                                          int n_nodes) {
    int g = blockIdx.x * blockDim.x + threadIdx.x;
    int f = g & 63;
    int wave = g >> 6;
    int nwaves = (gridDim.x * blockDim.x) >> 6;
    int chunk = (n_nodes + nwaves - 1) / nwaves;
    int n0 = wave * chunk;
    int n1 = n0 + chunk;
    if (n1 > n_nodes) n1 = n_nodes;
    if (n0 >= n_nodes) return;
    float mean = stats[f] * (1.0f / N_NODES);
    float var = stats[64 + f] * (1.0f / N_NODES) - mean * mean;
    float sc = gamma[f] * rsqrtf(var + EPS);
    float sh = beta[f] - mean * sc;
    int curg = batch[n0];
    float racc = 0.f;
    for (int n = n0; n < n1; n++) {
        int bg = batch[n];
        if (bg != curg) {
            atomicAdd(&gemb[(size_t)curg * HID + f], racc);
            racc = 0.f;
            curg = bg;
        }
        size_t idx = (size_t)n * HID + f;
        float v = h[idx] * sc + sh;
        v = fmaxf(v, 0.f);
        h[idx] = v;
        racc += v;
    }
    atomicAdd(&gemb[(size_t)curg * HID + f], racc);
}

__global__ __launch_bounds__(256) void final_kernel(const float* __restrict__ gemb,
                                                    const float* __restrict__ fcW,
                                                    const float* __restrict__ fcb,
                                                    float* __restrict__ out) {
    int g = blockIdx.x * blockDim.x + threadIdx.x;
    if (g >= N_GRAPHS * N_CLS) return;
    int gr = g >> 1, c = g & 1;
    float acc = fcb[c];
#pragma unroll
    for (int k = 0; k < HID; k++) acc += gemb[gr * HID + k] * fcW[k * N_CLS + c];
    out[g] = acc;
}

// ---------------- launch ----------------

extern "C" void kernel_launch(void* const* d_in, const int* in_sizes, int n_in,
                              void* d_out, int out_size, void* d_ws, size_t ws_size,
                              hipStream_t stream) {
    const float* x    = (const float*)d_in[0];
    const int*   ei   = (const int*)d_in[1];
    const int*   batch= (const int*)d_in[2];
    const float* ew   = (const float*)d_in[3];
    const float* W1   = (const float*)d_in[4];
    const float* b1   = (const float*)d_in[5];
    const float* W2   = (const float*)d_in[6];
    const float* b2   = (const float*)d_in[7];
    const float* W3   = (const float*)d_in[8];
    const float* b3   = (const float*)d_in[9];
    const float* g1   = (const float*)d_in[10];
    const float* bt1  = (const float*)d_in[11];
    const float* g2   = (const float*)d_in[12];
    const float* bt2  = (const float*)d_in[13];
    const float* g3   = (const float*)d_in[14];
    const float* bt3  = (const float*)d_in[15];
    const float* fcW  = (const float*)d_in[16];
    const float* fcb  = (const float*)d_in[17];

    const int* row = ei;
    const int* col = ei + N_EDGES;

    // d_out layout: out [2048*2] | node_embs [100000*64] | graph_emb [2048*64]
    float* out_head  = (float*)d_out;
    float* node_embs = out_head + N_GRAPHS * N_CLS;
    float* gemb      = node_embs + (size_t)N_NODES * HID;

    // ws layout (all 8B-aligned in this order)
    half_t* xwh  = (half_t*)d_ws;                             // 12.8 MB (4 planes)
    int2*  edges = (int2*)(xwh + (size_t)N_NODES * HID);      // 12.8 MB
    unsigned long long* packed = (unsigned long long*)(edges + N_EDGES); // 800 KB
    float* dinv  = (float*)(packed + N_NODES);                // 400 KB
    float* stats = dinv + N_NODES;                            // 512 B
    int*   ptr   = (int*)(stats + 128);                       // 400 KB (+1)
    int*   rank  = ptr + N_NODES + 1;                         // 6.4 MB
    int*   bsum  = rank + N_EDGES;                            // 512 B

    const int B   = 256;
    const int gN  = (N_NODES + B - 1) / B;
    const int NBS = (N_NODES + 1023) / 1024;  // 98 scan blocks
    const int gGS = 1024;                     // grid-stride
    const int gGA = 2048;                     // gather (mult of 8; 32 waves/CU)

    // ---- CSR build: 1 packed atomic per edge, atomic-free permute ----
    hipMemsetAsync(packed, 0, N_NODES * sizeof(unsigned long long), stream);
    hist_rank_kernel<<<gGS, B, 0, stream>>>(col, ew, packed, rank, N_EDGES);
    dinv_from_packed<<<gN, B, 0, stream>>>(packed, dinv, N_NODES);
    blocksum1024_kernel<<<NBS, B, 0, stream>>>(packed, bsum, N_NODES);
    topscan_kernel<<<1, 512, 0, stream>>>(bsum, NBS);
    blockscan1024_kernel<<<NBS, B, 0, stream>>>(packed, bsum, ptr, N_NODES, N_EDGES);
    permute_kernel<<<gGS, B, 0, stream>>>(row, col, ew, dinv, ptr, rank, edges, N_EDGES);

    float* h = node_embs;  // raw (pre-BN) activation; ends as h3 output

    // ---- layer 1 ----
    gemm_kernel<IN_F><<<gGS, B, 0, stream>>>(x, W1, xwh, N_NODES);
    hipMemsetAsync(stats, 0, 128 * sizeof(float), stream);
    gather_stats_kernel<<<gGA, B, 0, stream>>>(ptr, edges, xwh, dinv, b1, h, stats, N_NODES);

    // ---- layer 2 (BN1+ReLU fused into MFMA GEMM) ----
    gemm_bn_mfma_kernel<<<gGS, B, 0, stream>>>(h, W2, stats, g1, bt1, xwh, N_NODES);
    hipMemsetAsync(stats, 0, 128 * sizeof(float), stream);
    gather_stats_kernel<<<gGA, B, 0, stream>>>(ptr, edges, xwh, dinv, b2, h, stats, N_NODES);

    // ---- layer 3 (BN2+ReLU fused into MFMA GEMM) ----
    gemm_bn_mfma_kernel<<<gGS, B, 0, stream>>>(h, W3, stats, g2, bt2, xwh, N_NODES);
    hipMemsetAsync(stats, 0, 128 * sizeof(float), stream);
    gather_stats_kernel<<<gGA, B, 0, stream>>>(ptr, edges, xwh, dinv, b3, h, stats, N_NODES);

    // ---- BN3 + ReLU + node_embs + segment-sum ----
    hipMemsetAsync(gemb, 0, (size_t)N_GRAPHS * HID * sizeof(float), stream);
    bn_relu_seg_kernel<<<gGS, B, 0, stream>>>(h, stats, g3, bt3, batch, gemb, N_NODES);

    // ---- readout ----
    final_kernel<<<(N_GRAPHS * N_CLS + B - 1) / B, B, 0, stream>>>(gemb, fcW, fcb, out_head);
}